// Round 4
// baseline (4265.522 us; speedup 1.0000x reference)
//
#include <hip/hip_runtime.h>
#include <math.h>

// Problem constants
#define CB 16
#define CS 400
#define CT 51
#define CTM1 50
#define CV 50000
#define CE 128
#define CH 256
#define CMAXOOV 50
#define CEXT (CV + CMAXOOV)
#define NCHUNK 8
#define SCHUNK 50          // CS / NCHUNK
#define CX 640             // E + H + H  (x = [emb|ctx|h])
#define AXP 648            // padded LDS row (shorts) for x (81 short8)
#define VCHUNK 6256        // ~CEXT/8
#define NB2 782            // ceil(V/64)

typedef __attribute__((ext_vector_type(4))) float f32x4;
typedef __attribute__((ext_vector_type(8))) short short8;

__device__ __forceinline__ float wave_sum(float x) {
#pragma unroll
  for (int o = 32; o > 0; o >>= 1) x += __shfl_xor(x, o);
  return x;
}
__device__ __forceinline__ float sigm(float x) { return 1.f / (1.f + expf(-x)); }
__device__ __forceinline__ unsigned short f2bf(float f) {
  union { float f; unsigned u; } x;
  x.f = f;
  unsigned r = x.u + 0x7FFFu + ((x.u >> 16) & 1u);  // RNE
  return (unsigned short)(r >> 16);
}

// ---------------------------------------------------------------------------
// One-time weight prep
// ---------------------------------------------------------------------------
__global__ __launch_bounds__(256) void pw_convert(
    const float* __restrict__ W, unsigned short* __restrict__ Wb) {
  size_t i = ((size_t)blockIdx.x * 256 + threadIdx.x) * 8;
  float4 a = *(const float4*)(W + i);
  float4 b = *(const float4*)(W + i + 4);
  short8 o;
  o[0] = (short)f2bf(a.x); o[1] = (short)f2bf(a.y);
  o[2] = (short)f2bf(a.z); o[3] = (short)f2bf(a.w);
  o[4] = (short)f2bf(b.x); o[5] = (short)f2bf(b.y);
  o[6] = (short)f2bf(b.z); o[7] = (short)f2bf(b.w);
  *(short8*)(Wb + i) = o;
}

// Wcat[j][k] bf16: k<384 -> W_ih[j][k], else W_hh[j][k-384]. 1024x640.
__global__ __launch_bounds__(256) void pw_cat(
    const float* __restrict__ W_ih, const float* __restrict__ W_hh,
    unsigned short* __restrict__ Wcat) {
  int t8 = blockIdx.x * 256 + threadIdx.x;  // 81920 short8
  int j = t8 / 80, k8 = t8 % 80;
  short8 o;
#pragma unroll
  for (int i = 0; i < 8; ++i) {
    int k = k8 * 8 + i;
    float v = (k < CE + CH) ? W_ih[(size_t)j * (CE + CH) + k]
                            : W_hh[(size_t)j * CH + (k - (CE + CH))];
    o[i] = (short)f2bf(v);
  }
  *(short8*)(Wcat + (size_t)t8 * 8) = o;
}

// 256x256 fp32 transpose: out[j][k] = in[k][j]
__global__ __launch_bounds__(256) void pw_t256(const float* __restrict__ in,
                                               float* __restrict__ out) {
  int j = blockIdx.x, k = threadIdx.x;
  out[j * CH + k] = in[k * CH + j];
}

// ---------------------------------------------------------------------------
// P0: Wh_h = enc @ W_h^T via transposed W_h (coalesced); copy_idx; cov=0.
// ---------------------------------------------------------------------------
__global__ __launch_bounds__(256) void p0_precompute(
    const float* __restrict__ enc, const float* __restrict__ W_hT,
    const int* __restrict__ src_ids, const int* __restrict__ src_oov,
    float* __restrict__ Wh_h, float* __restrict__ cov,
    int* __restrict__ copy_idx) {
  const int row0 = blockIdx.x * 8, tid = threadIdx.x;
  __shared__ float erT[CH * 8];
#pragma unroll
  for (int i = 0; i < 8; ++i) {
    int idx = tid + i * 256;           // idx = r*256 + j
    int r = idx >> 8, j = idx & 255;
    erT[j * 8 + r] = enc[(size_t)row0 * CH + idx];
  }
  if (tid < 8) {
    int row = row0 + tid;
    int ov = src_oov[row];
    copy_idx[row] = (ov >= 0) ? (CV + ov) : src_ids[row];
    cov[row] = 0.f;
  }
  __syncthreads();
  float acc[8] = {0, 0, 0, 0, 0, 0, 0, 0};
#pragma unroll 4
  for (int j = 0; j < CH; ++j) {
    float w = W_hT[j * CH + tid];
    float4 e0 = *(const float4*)&erT[j * 8];
    float4 e1 = *(const float4*)&erT[j * 8 + 4];
    acc[0] += e0.x * w; acc[1] += e0.y * w; acc[2] += e0.z * w; acc[3] += e0.w * w;
    acc[4] += e1.x * w; acc[5] += e1.y * w; acc[6] += e1.z * w; acc[7] += e1.w * w;
  }
#pragma unroll
  for (int r = 0; r < 8; ++r) Wh_h[(size_t)(row0 + r) * CH + tid] = acc[r];
}

// ---------------------------------------------------------------------------
// P1: h0/c init, hWs from h0, zero parity-0 accumulators. grid=16.
// ---------------------------------------------------------------------------
__global__ __launch_bounds__(256) void p1_init(
    const float* __restrict__ hidden, const float* __restrict__ cell,
    const float* __restrict__ W_sT, float* __restrict__ h0,
    float* __restrict__ c, float* __restrict__ hWs, float* __restrict__ ssum0,
    float* __restrict__ uctx0, float* __restrict__ rowsum0) {
  const int b = blockIdx.x, tid = threadIdx.x;
  __shared__ float h_sh[CH];
  float hv = hidden[b * CH + tid];
  h_sh[tid] = hv;
  h0[b * CH + tid] = hv;
  c[b * CH + tid] = cell[b * CH + tid];
  uctx0[b * CH + tid] = 0.f;
  if (tid == 0) { ssum0[b] = 0.f; rowsum0[b] = 0.f; }
  __syncthreads();
  float acc = 0.f;
#pragma unroll 8
  for (int j = 0; j < CH; ++j) acc += h_sh[j] * W_sT[j * CH + tid];
  hWs[b * CH + tid] = acc;
}

// ---------------------------------------------------------------------------
// KA: normalize prev dist row + cov update + covloss(t-1) + scores (no-max
//     exp) -> atomic ssum + partial unnormalized ctx atomics.
// grid = 128 (b*8+chunk), 256 threads.
// ---------------------------------------------------------------------------
__global__ __launch_bounds__(256) void ka_scores(
    int t, const float* __restrict__ Wh_h, const float* __restrict__ hWs,
    float* __restrict__ cov, const float* __restrict__ w_c,
    const float* __restrict__ v_vec, const float* __restrict__ b_attn,
    const int* __restrict__ src_lens, const float* __restrict__ enc,
    const float* __restrict__ explog, const float* __restrict__ p_gen,
    const float* __restrict__ rowsum_prev,
    const float* __restrict__ escore_prev, float* __restrict__ escore_cur,
    const float* __restrict__ ssum_prev, float* __restrict__ ssum_cur,
    float* __restrict__ uctx_cur, float* __restrict__ covloss_p,
    float* __restrict__ dout) {
  const int b = blockIdx.x >> 3, chunk = blockIdx.x & 7;
  const int tid = threadIdx.x, lane = tid & 63, wid = tid >> 6;
  const int s0 = chunk * SCHUNK;
  __shared__ float hws_sh[CH], wc_sh[CH], vv_sh[CH];
  __shared__ float sh_cov[SCHUNK], sh_e[SCHUNK];
  hws_sh[tid] = hWs[b * CH + tid];
  wc_sh[tid] = w_c[tid];
  vv_sh[tid] = v_vec[tid];
  if (t > 0) {  // normalize dout row (b, t-1): p_gen * explog / rowsum
    float inv = p_gen[b] / rowsum_prev[b];
    float* drow = dout + ((size_t)(b * CTM1 + t - 1)) * CEXT;
    int vs = chunk * VCHUNK, ve = (chunk == 7) ? CEXT : vs + VCHUNK;
    for (int vv = vs + tid; vv < ve; vv += 256)
      drow[vv] = (vv < CV) ? explog[(size_t)b * CV + vv] * inv : 0.f;
  }
  float covp = 0.f;
  if (tid < SCHUNK) {
    int s = s0 + tid;
    float cv = cov[b * CS + s];
    if (t > 0) {
      float ap = escore_prev[b * CS + s] * (1.f / ssum_prev[b]);
      covp = fminf(ap, cv);
      cv += ap;
      cov[b * CS + s] = cv;
    }
    sh_cov[tid] = cv;
  }
  if (t > 0 && wid == 0) {
    float r = wave_sum(covp);
    if (tid == 0) covloss_p[((t - 1) * CB + b) * NCHUNK + chunk] = r;
  }
  __syncthreads();
  const float ba = b_attn[0];
  const int len = src_lens[b];
  const int k = lane * 4;
  float psum = 0.f;
  for (int i = wid; i < SCHUNK; i += 4) {
    int s = s0 + i;
    float cv = sh_cov[i];
    float4 w = *(const float4*)(Wh_h + ((size_t)(b * CS + s)) * CH + k);
    float p = tanhf(w.x + hws_sh[k] + cv * wc_sh[k] + ba) * vv_sh[k] +
              tanhf(w.y + hws_sh[k + 1] + cv * wc_sh[k + 1] + ba) * vv_sh[k + 1] +
              tanhf(w.z + hws_sh[k + 2] + cv * wc_sh[k + 2] + ba) * vv_sh[k + 2] +
              tanhf(w.w + hws_sh[k + 3] + cv * wc_sh[k + 3] + ba) * vv_sh[k + 3];
    p = wave_sum(p);
    if (lane == 0) {
      float esc = (s < len) ? expf(p) : 0.f;  // |score| small: no max needed
      sh_e[i] = esc;
      escore_cur[b * CS + s] = esc;
      psum += esc;
    }
  }
  if (lane == 0) atomicAdd(&ssum_cur[b], psum);
  __syncthreads();
  // partial unnormalized context, thread owns k = tid
  float pc = 0.f;
  const float* er = enc + ((size_t)(b * CS + s0)) * CH + tid;
#pragma unroll 5
  for (int i = 0; i < SCHUNK; ++i) pc += sh_e[i] * er[(size_t)i * CH];
  atomicAdd(&uctx_cur[b * CH + tid], pc);
}

// ---------------------------------------------------------------------------
// KC: prev copy-scatter (batch bI) + x assembly + gates MFMA (remapped: block
//     bI owns cols {w*256 + bI*16 + [0,16)} for w=0..3) + cell + writes.
// grid = 16, 256 threads (4 waves).
// ---------------------------------------------------------------------------
__global__ __launch_bounds__(256) void kc_gates(
    int t, const int* __restrict__ tgt, const float* __restrict__ embedding,
    const unsigned short* __restrict__ Wcat, const float* __restrict__ b_ih,
    const float* __restrict__ b_hh, const float* __restrict__ uctx_cur,
    const float* __restrict__ ssum_cur, const float* __restrict__ escore_prev,
    const float* __restrict__ ssum_prev, const float* __restrict__ p_gen,
    const int* __restrict__ copy_idx, const float* __restrict__ h_old,
    float* __restrict__ h_new, float* __restrict__ c,
    float* __restrict__ ctx_ws, unsigned short* __restrict__ A_bf16,
    float* __restrict__ dout) {
  const int bI = blockIdx.x, tid = threadIdx.x, lane = tid & 63, wid = tid >> 6;
  __shared__ __align__(16) short x_sh[CB * AXP];
  __shared__ float gsh[4][CB][16];
  __shared__ float sh_invs[CB];
  __shared__ int sh_tok[CB];
  if (t > 0) {  // scatter prev copy dist for batch bI (row already normed)
    float pg1 = 1.f - p_gen[bI];
    float invp = 1.f / ssum_prev[bI];
    float* drow = dout + ((size_t)(bI * CTM1 + t - 1)) * CEXT;
    for (int s = tid; s < CS; s += 256)
      atomicAdd(drow + copy_idx[bI * CS + s],
                pg1 * escore_prev[bI * CS + s] * invp);
  }
  if (tid < CB) {
    sh_invs[tid] = 1.f / ssum_cur[tid];
    sh_tok[tid] = tgt[tid * CT + t];
  }
  __syncthreads();
  for (int idx = tid; idx < CB * CE; idx += 256) {
    int bb = idx >> 7, k = idx & 127;
    x_sh[bb * AXP + k] = (short)f2bf(embedding[(size_t)sh_tok[bb] * CE + k]);
  }
  for (int idx = tid; idx < CB * CH; idx += 256) {
    int bb = idx >> 8, k = idx & 255;
    float cf = uctx_cur[bb * CH + k] * sh_invs[bb];
    x_sh[bb * AXP + CE + k] = (short)f2bf(cf);
    x_sh[bb * AXP + CE + CH + k] = (short)f2bf(h_old[bb * CH + k]);
    if ((k >> 4) == bI) {
      ctx_ws[bb * CH + k] = cf;
      A_bf16[bb * 2 * CH + CH + k] = f2bf(cf);
    }
  }
  __syncthreads();
  {  // MFMA: wave w -> gate group w, cols n0..n0+15
    const int nn = lane & 15, g = lane >> 4;
    const int n0 = wid * 256 + bI * 16;
    const short8* ap8 = (const short8*)(x_sh + nn * AXP);
    const short8* bp8 = (const short8*)Wcat + (size_t)(n0 + nn) * 80;
    f32x4 acc = {0.f, 0.f, 0.f, 0.f};
#pragma unroll
    for (int kt = 0; kt < 20; ++kt)
      acc = __builtin_amdgcn_mfma_f32_16x16x32_bf16(ap8[kt * 4 + g],
                                                    bp8[kt * 4 + g], acc,
                                                    0, 0, 0);
    float bias = b_ih[n0 + nn] + b_hh[n0 + nn];
#pragma unroll
    for (int r = 0; r < 4; ++r) gsh[wid][g * 4 + r][nn] = acc[r] + bias;
  }
  __syncthreads();
  {  // cell update: tid = b*16 + kk, k_global = bI*16+kk
    int bb = tid >> 4, kk = tid & 15, kg = bI * 16 + kk;
    float gi = gsh[0][bb][kk], gf = gsh[1][bb][kk];
    float gg = gsh[2][bb][kk], go = gsh[3][bb][kk];
    float co = c[bb * CH + kg];
    float cn = sigm(gf) * co + sigm(gi) * tanhf(gg);
    float hn = sigm(go) * tanhf(cn);
    c[bb * CH + kg] = cn;
    h_new[bb * CH + kg] = hn;
    A_bf16[bb * 2 * CH + kg] = f2bf(hn);
  }
}

// ---------------------------------------------------------------------------
// K2: main blocks: explog = exp(A.Wb^T + b_out), rowsum atomics.
//     extra 16 blocks: hWs = h_new @ W_sT;  last block: p_gen + zeroing.
// grid = NB2 + 17, 256 threads.
// ---------------------------------------------------------------------------
__global__ __launch_bounds__(256) void k2_big(
    int t, const unsigned short* __restrict__ Wb,
    const float* __restrict__ b_out, const unsigned short* __restrict__ A,
    const int* __restrict__ tgt, const float* __restrict__ embedding,
    const float* __restrict__ h_new, const float* __restrict__ ctx_ws,
    const float* __restrict__ W_sT, const float* __restrict__ W_pg,
    const float* __restrict__ b_pg, float* __restrict__ explog,
    float* __restrict__ rowsum_cur, float* __restrict__ hWs,
    float* __restrict__ p_gen, float* __restrict__ ssum_next,
    float* __restrict__ uctx_next, float* __restrict__ rowsum_next) {
  const int bid = blockIdx.x;
  const int tid = threadIdx.x;
  if (bid < NB2) {
    const int lane = tid & 63, wid = tid >> 6;
    const int n = lane & 15, g = lane >> 4;
    const int v = bid * 64 + wid * 16 + n;
    const bool ok = v < CV;
    const int vc = ok ? v : CV - 1;
    const short8* ap = (const short8*)A;
    const short8* bp = (const short8*)Wb;
    short8 af[16], bf[16];
#pragma unroll
    for (int kt = 0; kt < 16; ++kt) af[kt] = ap[n * 64 + kt * 4 + g];
#pragma unroll
    for (int kt = 0; kt < 16; ++kt) bf[kt] = bp[(size_t)vc * 64 + kt * 4 + g];
    f32x4 acc = {0.f, 0.f, 0.f, 0.f};
#pragma unroll
    for (int kt = 0; kt < 16; ++kt)
      acc = __builtin_amdgcn_mfma_f32_16x16x32_bf16(af[kt], bf[kt], acc,
                                                    0, 0, 0);
    float bo = ok ? b_out[v] : 0.f;
    float ev[4];
#pragma unroll
    for (int r = 0; r < 4; ++r) {
      float e = ok ? expf(acc[r] + bo) : 0.f;
      ev[r] = e;
      if (ok) explog[(size_t)(g * 4 + r) * CV + v] = e;
    }
#pragma unroll
    for (int r = 0; r < 4; ++r) {
#pragma unroll
      for (int o = 1; o < 16; o <<= 1) ev[r] += __shfl_xor(ev[r], o);
    }
    __shared__ float prs[4][16];
    if ((lane & 15) == 0) {
#pragma unroll
      for (int r = 0; r < 4; ++r) prs[wid][g * 4 + r] = ev[r];
    }
    __syncthreads();
    if (tid < 16) {
      float s = prs[0][tid] + prs[1][tid] + prs[2][tid] + prs[3][tid];
      atomicAdd(&rowsum_cur[tid], s);
    }
    return;
  }
  if (bid < NB2 + 16) {  // hWs block e: cols e*16..e*16+15
    __shared__ float hsh[CB * CH];
    for (int i = tid; i < CB * CH; i += 256) hsh[i] = h_new[i];
    __syncthreads();
    const int e = bid - NB2;
    int bb = tid >> 4, kk = tid & 15, kp = e * 16 + kk;
    float acc = 0.f;
#pragma unroll 4
    for (int j = 0; j < CH; ++j) acc += hsh[bb * CH + j] * W_sT[j * CH + kp];
    hWs[bb * CH + kp] = acc;
    return;
  }
  {  // p_gen + zero next-parity accumulators
    int bb = tid >> 4, j = tid & 15;
    int tok = tgt[bb * CT + t];
    float z = 0.f;
    for (int k = j; k < CH; k += 16)
      z += h_new[bb * CH + k] * W_pg[k] + ctx_ws[bb * CH + k] * W_pg[CH + k];
    for (int k = j; k < CE; k += 16)
      z += embedding[(size_t)tok * CE + k] * W_pg[2 * CH + k];
#pragma unroll
    for (int o = 1; o < 16; o <<= 1) z += __shfl_xor(z, o);
    if (j == 0) p_gen[bb] = sigm(z + b_pg[0]);
    for (int i = tid; i < CB * CH; i += 256) uctx_next[i] = 0.f;
    if (tid < CB) { ssum_next[tid] = 0.f; rowsum_next[tid] = 0.f; }
  }
}

// ---------------------------------------------------------------------------
// K4a: normalize final dist row + covloss(49). grid = 128.
// ---------------------------------------------------------------------------
__global__ __launch_bounds__(256) void k4a_final(
    const float* __restrict__ explog, const float* __restrict__ p_gen,
    const float* __restrict__ rowsum1, const float* __restrict__ escore1,
    const float* __restrict__ ssum1, const float* __restrict__ cov,
    float* __restrict__ covloss_p, float* __restrict__ dout) {
  const int b = blockIdx.x >> 3, chunk = blockIdx.x & 7;
  const int tid = threadIdx.x, wid = tid >> 6;
  float inv = p_gen[b] / rowsum1[b];
  float* drow = dout + ((size_t)(b * CTM1 + CTM1 - 1)) * CEXT;
  int vs = chunk * VCHUNK, ve = (chunk == 7) ? CEXT : vs + VCHUNK;
  for (int vv = vs + tid; vv < ve; vv += 256)
    drow[vv] = (vv < CV) ? explog[(size_t)b * CV + vv] * inv : 0.f;
  float covp = 0.f;
  if (tid < SCHUNK) {
    int s = chunk * SCHUNK + tid;
    float a = escore1[b * CS + s] * (1.f / ssum1[b]);
    covp = fminf(a, cov[b * CS + s]);
  }
  if (wid == 0) {
    float r = wave_sum(covp);
    if (tid == 0) covloss_p[(49 * CB + b) * NCHUNK + chunk] = r;
  }
}

// ---------------------------------------------------------------------------
// K4b: final scatter + hT/cT + coverage_loss. grid = 16.
// ---------------------------------------------------------------------------
__global__ __launch_bounds__(256) void k4b_tail(
    const float* __restrict__ h_fin, const float* __restrict__ c,
    const float* __restrict__ escore1, const float* __restrict__ ssum1,
    const float* __restrict__ p_gen, const int* __restrict__ copy_idx,
    const float* __restrict__ covloss_p, float* __restrict__ dout) {
  const int b = blockIdx.x, tid = threadIdx.x, lane = tid & 63, wid = tid >> 6;
  __shared__ float red[4];
  float pg1 = 1.f - p_gen[b];
  float invp = 1.f / ssum1[b];
  float* drow = dout + ((size_t)(b * CTM1 + CTM1 - 1)) * CEXT;
  for (int s = tid; s < CS; s += 256)
    atomicAdd(drow + copy_idx[b * CS + s], pg1 * escore1[b * CS + s] * invp);
  const size_t D0 = (size_t)CB * CTM1 * CEXT;
  dout[D0 + b * CH + tid] = h_fin[b * CH + tid];
  dout[D0 + CB * CH + b * CH + tid] = c[b * CH + tid];
  if (b == 0) {
    float p = 0.f;
    for (int i = tid; i < CTM1 * CB * NCHUNK; i += 256) p += covloss_p[i];
    p = wave_sum(p);
    if (lane == 0) red[wid] = p;
    __syncthreads();
    if (tid == 0)
      dout[D0 + 2 * CB * CH] =
          (red[0] + red[1] + red[2] + red[3]) / (float)(CTM1 * CB);
  }
}

// ---------------------------------------------------------------------------
extern "C" void kernel_launch(void* const* d_in, const int* in_sizes, int n_in,
                              void* d_out, int out_size, void* d_ws,
                              size_t ws_size, hipStream_t stream) {
  const int* tgt = (const int*)d_in[0];
  const float* hidden = (const float*)d_in[1];
  const float* cell = (const float*)d_in[2];
  const float* enc = (const float*)d_in[3];
  const int* src_lens = (const int*)d_in[4];
  const int* src_ids = (const int*)d_in[5];
  const int* src_oov = (const int*)d_in[6];
  const float* embedding = (const float*)d_in[7];
  const float* W_h = (const float*)d_in[8];
  const float* W_s = (const float*)d_in[9];
  const float* w_c = (const float*)d_in[10];
  const float* v_vec = (const float*)d_in[11];
  const float* b_attn = (const float*)d_in[12];
  const float* W_ih = (const float*)d_in[13];
  const float* W_hh = (const float*)d_in[14];
  const float* b_ih = (const float*)d_in[15];
  const float* b_hh = (const float*)d_in[16];
  const float* W_pg = (const float*)d_in[17];
  const float* b_pg = (const float*)d_in[18];
  const float* W_out = (const float*)d_in[19];
  const float* b_out = (const float*)d_in[20];
  float* dout = (float*)d_out;

  // workspace layout (all sub-arrays multiples of 16B)
  float* ws = (float*)d_ws;
  float* Wh_h = ws;                                  // 1,638,400
  float* escore = Wh_h + (size_t)CB * CS * CH;       // 2*B*S = 12,800
  float* h2 = escore + 2 * CB * CS;                  // 2*B*H = 8,192
  float* c = h2 + 2 * CB * CH;                       // 4,096
  float* cov = c + CB * CH;                          // 6,400
  float* uctx = cov + CB * CS;                       // 2*B*H = 8,192
  float* ssum = uctx + 2 * CB * CH;                  // 32
  float* rowsum = ssum + 2 * CB;                     // 32
  float* p_gen = rowsum + 2 * CB;                    // 16
  float* hWs = p_gen + CB;                           // 4,096
  float* covloss_p = hWs + CB * CH;                  // 6,400
  float* ctx_ws = covloss_p + CTM1 * CB * NCHUNK;    // 4,096
  float* explog = ctx_ws + CB * CH;                  // 800,000
  float* W_sT = explog + (size_t)CB * CV;            // 65,536
  int* copy_idx = (int*)(W_sT + CH * CH);            // 6,400 ints
  unsigned short* A_bf16 = (unsigned short*)(copy_idx + CB * CS);  // 8,192
  unsigned short* Wcat = A_bf16 + CB * 2 * CH;       // 655,360
  unsigned short* Wb = Wcat + (size_t)(4 * CH) * CX; // 25,600,000
  float* W_hT = explog;  // aliased: explog first written after p0 consumed it

  // one-time weight prep
  pw_convert<<<(CV * 2 * CH) / (256 * 8), 256, 0, stream>>>(W_out, Wb);
  pw_cat<<<((4 * CH) * CX / 8) / 256, 256, 0, stream>>>(W_ih, W_hh, Wcat);
  pw_t256<<<CH, CH, 0, stream>>>(W_s, W_sT);
  pw_t256<<<CH, CH, 0, stream>>>(W_h, W_hT);

  p0_precompute<<<CB * CS / 8, 256, 0, stream>>>(enc, W_hT, src_ids, src_oov,
                                                 Wh_h, cov, copy_idx);
  p1_init<<<CB, 256, 0, stream>>>(hidden, cell, W_sT, h2, c, hWs, ssum, uctx,
                                  rowsum);

  for (int t = 0; t < CTM1; ++t) {
    const int par = t & 1, prev = par ^ 1;
    ka_scores<<<CB * NCHUNK, 256, 0, stream>>>(
        t, Wh_h, hWs, cov, w_c, v_vec, b_attn, src_lens, enc, explog, p_gen,
        rowsum + prev * CB, escore + prev * CB * CS, escore + par * CB * CS,
        ssum + prev * CB, ssum + par * CB, uctx + par * CB * CH, covloss_p,
        dout);
    kc_gates<<<CB, 256, 0, stream>>>(
        t, tgt, embedding, Wcat, b_ih, b_hh, uctx + par * CB * CH,
        ssum + par * CB, escore + prev * CB * CS, ssum + prev * CB, p_gen,
        copy_idx, h2 + par * CB * CH, h2 + prev * CB * CH, c, ctx_ws, A_bf16,
        dout);
    k2_big<<<NB2 + 17, 256, 0, stream>>>(
        t, Wb, b_out, A_bf16, tgt, embedding, h2 + prev * CB * CH, ctx_ws,
        W_sT, W_pg, b_pg, explog, rowsum + par * CB, hWs, p_gen,
        ssum + prev * CB, uctx + prev * CB * CH, rowsum + prev * CB);
  }
  // t=49: par=1. Final row normalize + covloss(49) + tail.
  k4a_final<<<CB * NCHUNK, 256, 0, stream>>>(explog, p_gen, rowsum + CB,
                                             escore + CB * CS, ssum + CB, cov,
                                             covloss_p, dout);
  k4b_tail<<<CB, 256, 0, stream>>>(h2, c, escore + CB * CS, ssum + CB, p_gen,
                                   copy_idx, covloss_p, dout);
}